// Round 9
// baseline (680.964 us; speedup 1.0000x reference)
//
#include <hip/hip_runtime.h>

// GrCNN: B=32, L=128, D=256, 127 sequential levels.
// Round 9: row-slab (256 blocks = (b,h), 16 rows, 8 waves x 32 cols) with:
//  - transposed gate MFMA (operand swap; A/B frag layouts are symmetric):
//    lane rho holds all 3 gate preacts of row rho -> in-lane softmax in 16
//    lanes, 2-shfl broadcast (g2 = 1-g0-g1).
//  - rv via shifted one-hot extraction (rows lr+1) -> no boundary reads/shfls.
//  - ONE barrier per level: boundary import at level tail into DST row 16;
//    export-slot ack gate = per-wave lane-0 poll at level head.
//  - precomputed ds addresses (rd[16], wo[2][4]) + ping-pong via ^16384.
//  - __launch_bounds__(512,2): VGPR cap 256 so W fragments can be resident.

#define B_ 32
#define L_ 128
#define D_ 256
#define NTHR 512
#define BUFB 16384
#define LOG2E 1.4426950408889634f
#define PS_SLOTS 568   // sum_{h=0}^{7} (127-16h)

typedef _Float16 half8 __attribute__((ext_vector_type(8)));
typedef float f32x4 __attribute__((ext_vector_type(4)));

#define SWZ(o)  ((o) ^ ((((o) >> 9) & 7) << 4))
#define MFMA16 __builtin_amdgcn_mfma_f32_16x16x32_f16

// ---- WT[272][512] fp16: col j -> 512 k (k<256: Wl/Gl row k, else Wr/Gr) ----
__global__ void prep_wt(const float* __restrict__ Wl, const float* __restrict__ Wr,
                        const float* __restrict__ Gl, const float* __restrict__ Gr,
                        _Float16* __restrict__ WT) {
    int j = blockIdx.x;
    for (int k = threadIdx.x; k < 512; k += 256) {
        float v = 0.f;
        if (j < 256) v = (k < 256) ? Wl[k * 256 + j] : Wr[(k - 256) * 256 + j];
        else { int jj = j - 256; if (jj < 3) v = (k < 256) ? Gl[k * 3 + jj] : Gr[(k - 256) * 3 + jj]; }
        WT[(size_t)j * 512 + k] = (_Float16)v;
    }
}

// ---- init: zero flags+acks, level-0 col max ----
__global__ void init_misc(const float* __restrict__ x, float* __restrict__ out,
                          int* __restrict__ flags) {
    int b = blockIdx.x, c = threadIdx.x;
    if (b == 0) for (int i = c; i < 2 * 256 * 16; i += 256) flags[i] = 0;
    float m = -3.4e38f;
    for (int row = 0; row < L_; ++row)
        m = fmaxf(m, x[((size_t)b * L_ + row) * D_ + c]);
    out[(size_t)b * L_ * D_ + c] = m;
}

// ---- decode: pmax (fp16-packed partials per (b,slot)) -> out levels 1..127 ----
__global__ void decode_out(const unsigned* __restrict__ pmax, float* __restrict__ out) {
    for (size_t i = (size_t)blockIdx.x * 256 + threadIdx.x; i < (size_t)32 * 127 * 256;
         i += (size_t)gridDim.x * 256) {
        int c = (int)(i & 255);
        int k = (int)((i >> 8) % 127) + 1;
        int b = (int)(i / (127 * 256));
        int hcnt = (143 - k) >> 4;              // ceil((128-k)/16)
        int dw = ((c >> 5) * 16) + (c & 15);
        int hi = (c >> 4) & 1;
        float mx = -3.4e38f;
        for (int h = 0; h < hcnt; ++h) {
            int slot = 127 * h - 8 * h * (h - 1) + (k - 1);
            unsigned u = pmax[((size_t)b * PS_SLOTS + slot) * 128 + dw];
            unsigned short us = hi ? (unsigned short)(u >> 16) : (unsigned short)(u & 0xffff);
            float v = (float)__builtin_bit_cast(_Float16, us);
            mx = fmaxf(mx, v);
        }
        out[((size_t)b * 128 + k) * 256 + c] = mx;
    }
}

__global__ __launch_bounds__(NTHR, 2) void grcnn_main(
    const float* __restrict__ x, const _Float16* __restrict__ WT,
    const float* __restrict__ Wb, const float* __restrict__ Gb,
    unsigned* __restrict__ pmax, unsigned* __restrict__ brow,
    int* __restrict__ flags)
{
    __shared__ alignas(16) char lds[BUFB + 8704];   // bufA @0, bufB @BUFB

    const int tid = threadIdx.x;
    const int b = blockIdx.x & 31, h = blockIdx.x >> 5;
    const int w = tid >> 6, l = tid & 63, lr = l & 15, q = l >> 4;
    const int cw = w * 32;

    // ---- W fragments (resident under the 256-VGPR cap) ----
    half8 wf0[16], wf1[16], wfg[16];
    #pragma unroll
    for (int s = 0; s < 16; ++s) {
        const _Float16* p = WT + s * 32 + q * 8;
        wf0[s] = *(const half8*)(p + (size_t)(cw + lr) * 512);
        wf1[s] = *(const half8*)(p + (size_t)(cw + 16 + lr) * 512);
        wfg[s] = *(const half8*)(p + (size_t)(256 + lr) * 512);
    }
    // one-hot extraction frags (as B: selects k == col, k == 16+col)
    half8 oh0 = {}, oh1 = {};
    {
        _Float16 one = (_Float16)1.0f;
        #pragma unroll
        for (int j = 0; j < 8; ++j) if (j == (lr & 7)) {
            if (q == (lr >> 3))     oh0[j] = one;
            if (q == 2 + (lr >> 3)) oh1[j] = one;
        }
    }
    const float wb0 = Wb[cw + lr], wb1 = Wb[cw + 16 + lr];
    const float gbi0 = Gb[0], gbi1 = Gb[1], gbi2 = Gb[2];

    // ---- precomputed LDS addresses (bufA-relative; toggle via ^BUFB) ----
    int rd[16];
    #pragma unroll
    for (int s = 0; s < 16; ++s) rd[s] = SWZ(lr * 512 + s * 64 + q * 16);
    const int rax  = SWZ(lr * 512 + w * 64 + q * 16);
    const int rax2 = SWZ((lr + 1) * 512 + w * 64 + q * 16);
    int wo[2][4];
    #pragma unroll
    for (int nt = 0; nt < 2; ++nt)
        #pragma unroll
        for (int r = 0; r < 4; ++r)
            wo[nt][r] = SWZ((q * 4 + r) * 512 + (cw + nt * 16 + lr) * 2);
    const int impA = 8192 + l * 8;          // row 16 (identity swizzle)

    int* flagP = &flags[(b * 8 + h) * 16];
    int* flagN = &flags[(b * 8 + h + 1) * 16];
    int* ackP  = &flags[(256 + b * 8 + h) * 16];
    int* ackC  = &flags[(256 + b * 8 + h - 1) * 16];
    const int slotbase = 127 * h - 8 * h * (h - 1);

    // ---- stage rows 16h..16h+16 (clamped) into BOTH buffers ----
    for (int ch = tid; ch < 17 * 32; ch += NTHR) {
        int row = ch >> 5, kc = ch & 31;
        int grow = 16 * h + row; if (grow > 127) grow = 127;
        const float* xp = x + ((size_t)b * L_ + grow) * D_ + kc * 8;
        half8 v;
        #pragma unroll
        for (int j = 0; j < 8; ++j) v[j] = (_Float16)xp[j];
        int off = SWZ(row * 512 + kc * 16);
        *(half8*)(lds + off) = v;
        *(half8*)(lds + BUFB + off) = v;
    }
    __syncthreads();

    int rb = 0;   // src base toggle; dst = rb ^ BUFB

    for (int t = 0; t < 127; ++t) {
        const int m = 127 - t - 16 * h;
        if (m <= 0) break;
        const int mm = (m > 16) ? 16 : m;
        const bool doExpN = (h >= 1) && (126 - t >= 16 * h);
        const bool doImpT = (h < 7) && (t <= 110 - 16 * h);
        const int rw = rb ^ BUFB;

        // ---- export-slot ack gate (ring depth 4), per wave, lane 0 ----
        if (doExpN && t >= 3 && l == 0) {
            while (__hip_atomic_load(ackC, __ATOMIC_RELAXED, __HIP_MEMORY_SCOPE_AGENT) < t - 3)
                __builtin_amdgcn_s_sleep(1);
        }

        // ---- MFMA: central tiles + transposed gate (operand swap) ----
        f32x4 a0 = {}, a1 = {}, ag = {};
        #pragma unroll
        for (int s = 0; s < 16; ++s) {
            half8 av = *(const half8*)(lds + (rd[s] ^ rb));
            a0 = MFMA16(av, wf0[s], a0, 0, 0, 0);
            a1 = MFMA16(av, wf1[s], a1, 0, 0, 0);
            ag = MFMA16(wfg[s], av, ag, 0, 0, 0);   // C[gate][sent-row]
        }
        half8 ax  = *(const half8*)(lds + (rax  ^ rb));
        half8 ax2 = *(const half8*)(lds + (rax2 ^ rb));
        f32x4 z = {};
        f32x4 e0 = MFMA16(ax,  oh0, z, 0, 0, 0);    // lv: S[row][cw+lr]
        f32x4 e1 = MFMA16(ax,  oh1, z, 0, 0, 0);    // lv: S[row][cw+16+lr]
        f32x4 f0 = MFMA16(ax2, oh0, z, 0, 0, 0);    // rv: S[row+1][cw+lr]
        f32x4 f1 = MFMA16(ax2, oh1, z, 0, 0, 0);    // rv: S[row+1][cw+16+lr]

        // ---- in-lane softmax (lanes 0..15 hold rows 0..15) ----
        float sg0 = 0.f, sg1 = 0.f;
        if (l < 16) {
            float p0 = ag[0] + gbi0, p1 = ag[1] + gbi1, p2 = ag[2] + gbi2;
            float mg = fmaxf(fmaxf(p0, p1), p2);
            float ee0 = exp2f((p0 - mg) * LOG2E);
            float ee1 = exp2f((p1 - mg) * LOG2E);
            float ee2 = exp2f((p2 - mg) * LOG2E);
            float inv = __builtin_amdgcn_rcpf(ee0 + ee1 + ee2);
            sg0 = ee0 * inv; sg1 = ee1 * inv;
        }

        // ---- epilogue ----
        float cm0 = -3.4e38f, cm1 = -3.4e38f;
        #pragma unroll
        for (int r = 0; r < 4; ++r) {
            const int row = q * 4 + r;
            float g0f = __shfl(sg0, row, 64);
            float g1f = __shfl(sg1, row, 64);
            float g2f = 1.f - g0f - g1f;
            if (row < mm) {
                #define EPI(NT, ACC, EV, FV, WBV, CMV) {                                     \
                    float pre = ACC[r] + WBV;                                                \
                    float exx = exp2f(pre * (2.f * LOG2E));                                  \
                    float ce = 1.f - 2.f * __builtin_amdgcn_rcpf(exx + 1.f);                 \
                    float nx = g0f * EV[r] + g1f * ce + g2f * FV[r];                         \
                    CMV = fmaxf(CMV, nx);                                                    \
                    int pdi = __builtin_amdgcn_update_dpp(                                   \
                        0, __builtin_bit_cast(int, nx), 0xB1, 0xF, 0xF, true);               \
                    float pnx = __builtin_bit_cast(float, pdi);                              \
                    unsigned pk = (unsigned)__builtin_bit_cast(unsigned short, (_Float16)nx) \
                        | ((unsigned)__builtin_bit_cast(unsigned short, (_Float16)pnx) << 16);\
                    if (!(lr & 1)) {                                                         \
                        *(unsigned*)(lds + (wo[NT][r] ^ rw)) = pk;                           \
                        if (r == 0 && q == 0 && doExpN) {                                    \
                            unsigned* ep = brow +                                            \
                                (((size_t)((t + 1) & 3) * 32 + b) * 8 + h) * 128             \
                                + (cw >> 1) + NT * 8 + (lr >> 1);                            \
                            __hip_atomic_store(ep, pk, __ATOMIC_RELAXED,                     \
                                               __HIP_MEMORY_SCOPE_AGENT);                    \
                        }                                                                    \
                    }                                                                        \
                }
                EPI(0, a0, e0, f0, wb0, cm0)
                EPI(1, a1, e1, f1, wb1, cm1)
                #undef EPI
            }
        }

        // ---- col-max -> private pmax slot ----
        cm0 = fmaxf(cm0, __shfl_xor(cm0, 16, 64));
        cm0 = fmaxf(cm0, __shfl_xor(cm0, 32, 64));
        cm1 = fmaxf(cm1, __shfl_xor(cm1, 16, 64));
        cm1 = fmaxf(cm1, __shfl_xor(cm1, 32, 64));
        if (l < 16) {
            unsigned ph = (unsigned)__builtin_bit_cast(unsigned short, (_Float16)cm0)
                        | ((unsigned)__builtin_bit_cast(unsigned short, (_Float16)cm1) << 16);
            pmax[((size_t)b * PS_SLOTS + slotbase + t) * 128 + w * 16 + l] = ph;
        }

        // ---- wave 0 tail: import state-(t+1) boundary into DST row 16 ----
        if (w == 0 && doImpT) {
            if (l == 0) {
                while (__hip_atomic_load(flagN, __ATOMIC_RELAXED, __HIP_MEMORY_SCOPE_AGENT) < t + 1)
                    __builtin_amdgcn_s_sleep(1);
            }
            const unsigned long long* bp = (const unsigned long long*)brow
                + (((size_t)((t + 1) & 3) * 32 + b) * 8 + (h + 1)) * 64 + l;
            unsigned long long iv =
                __hip_atomic_load(bp, __ATOMIC_RELAXED, __HIP_MEMORY_SCOPE_AGENT);
            *(unsigned long long*)(lds + (impA ^ rw)) = iv;   // waits vmcnt via data dep
            if (l == 0)
                __hip_atomic_store(ackP, t + 1, __ATOMIC_RELAXED, __HIP_MEMORY_SCOPE_AGENT);
        }

        __syncthreads();   // the ONE barrier: dst rows + import + exports drained

        if (tid == 0 && doExpN)
            __hip_atomic_store(flagP, t + 1, __ATOMIC_RELAXED, __HIP_MEMORY_SCOPE_AGENT);
        rb ^= BUFB;
    }
}

extern "C" void kernel_launch(void* const* d_in, const int* in_sizes, int n_in,
                              void* d_out, int out_size, void* d_ws, size_t ws_size,
                              hipStream_t stream) {
    const float* x  = (const float*)d_in[0];
    const float* Wl = (const float*)d_in[1];
    const float* Wr = (const float*)d_in[2];
    const float* Wb = (const float*)d_in[3];
    const float* Gl = (const float*)d_in[4];
    const float* Gr = (const float*)d_in[5];
    const float* Gb = (const float*)d_in[6];
    float* out = (float*)d_out;
    char* ws = (char*)d_ws;

    _Float16* WT = (_Float16*)ws;                         // 278,528 B
    unsigned* brow = (unsigned*)(ws + 278528);            // 524,288 B (ring 4)
    int* flags = (int*)(ws + 802816);                     // 32,768 B
    unsigned* pmax = (unsigned*)(ws + 835584);            // 9,306,112 B

    prep_wt<<<272, 256, 0, stream>>>(Wl, Wr, Gl, Gr, WT);
    init_misc<<<B_, 256, 0, stream>>>(x, out, flags);

    void* args[] = { (void*)&x, (void*)&WT, (void*)&Wb, (void*)&Gb,
                     (void*)&pmax, (void*)&brow, (void*)&flags };
    hipLaunchCooperativeKernel((const void*)grcnn_main, dim3(B_ * 8), dim3(NTHR),
                               args, 0, stream);

    decode_out<<<1024, 256, 0, stream>>>(pmax, out);
}

// Round 10
// 521.481 us; speedup vs baseline: 1.3058x; 1.3058x over previous
//
#include <hip/hip_runtime.h>

// GrCNN: B=32, L=128, D=256, 127 sequential levels.
// Round 10: row-slab (256 blocks=(b,h), 16 rows, 8 waves x 32 cols), with W
// ACTUALLY VGPR-resident: per-wave W cut to 136 VGPR (named scalars, no
// arrays) by moving gates to split-K across waves (wave w does K-steps
// 2w,2w+1 with an 8-VGPR gate fragment on its own av loads; partials summed
// deterministically via LDS gbuf[w][16] f32x4 slots; +1 mid barrier).
// Protocol (ring-4 flag/ack, tail import into dst row16, reg-export,
// private pmax + decode kernel) identical to rounds 8/9 (passed twice).

#define B_ 32
#define L_ 128
#define D_ 256
#define NTHR 512
#define BUFB 16384
#define GBUF 25088            // gbuf: [w][16] f32x4 = 2048 B
#define LOG2E 1.4426950408889634f
#define PS_SLOTS 568          // sum_{h=0}^{7} (127-16h)

typedef _Float16 half8 __attribute__((ext_vector_type(8)));
typedef float f32x4 __attribute__((ext_vector_type(4)));

#define SWZ(o)  ((o) ^ ((((o) >> 9) & 7) << 4))
#define MFMA16 __builtin_amdgcn_mfma_f32_16x16x32_f16

// ---- WT[272][512] fp16: col j -> 512 k (k<256: Wl/Gl row k, else Wr/Gr) ----
__global__ void prep_wt(const float* __restrict__ Wl, const float* __restrict__ Wr,
                        const float* __restrict__ Gl, const float* __restrict__ Gr,
                        _Float16* __restrict__ WT) {
    int j = blockIdx.x;
    for (int k = threadIdx.x; k < 512; k += 256) {
        float v = 0.f;
        if (j < 256) v = (k < 256) ? Wl[k * 256 + j] : Wr[(k - 256) * 256 + j];
        else { int jj = j - 256; if (jj < 3) v = (k < 256) ? Gl[k * 3 + jj] : Gr[(k - 256) * 3 + jj]; }
        WT[(size_t)j * 512 + k] = (_Float16)v;
    }
}

// ---- init: zero flags+acks, level-0 col max ----
__global__ void init_misc(const float* __restrict__ x, float* __restrict__ out,
                          int* __restrict__ flags) {
    int b = blockIdx.x, c = threadIdx.x;
    if (b == 0) for (int i = c; i < 2 * 256 * 16; i += 256) flags[i] = 0;
    float m = -3.4e38f;
    for (int row = 0; row < L_; ++row)
        m = fmaxf(m, x[((size_t)b * L_ + row) * D_ + c]);
    out[(size_t)b * L_ * D_ + c] = m;
}

// ---- decode: pmax (fp16-packed partials per (b,slot)) -> out levels 1..127 ----
__global__ void decode_out(const unsigned* __restrict__ pmax, float* __restrict__ out) {
    for (size_t i = (size_t)blockIdx.x * 256 + threadIdx.x; i < (size_t)32 * 127 * 256;
         i += (size_t)gridDim.x * 256) {
        int c = (int)(i & 255);
        int k = (int)((i >> 8) % 127) + 1;
        int b = (int)(i / (127 * 256));
        int hcnt = (143 - k) >> 4;              // ceil((128-k)/16)
        int dw = ((c >> 5) * 16) + (c & 15);
        int hi = (c >> 4) & 1;
        float mx = -3.4e38f;
        for (int h = 0; h < hcnt; ++h) {
            int slot = 127 * h - 8 * h * (h - 1) + (k - 1);
            unsigned u = pmax[((size_t)b * PS_SLOTS + slot) * 128 + dw];
            unsigned short us = hi ? (unsigned short)(u >> 16) : (unsigned short)(u & 0xffff);
            float v = (float)__builtin_bit_cast(_Float16, us);
            mx = fmaxf(mx, v);
        }
        out[((size_t)b * 128 + k) * 256 + c] = mx;
    }
}

__global__ __launch_bounds__(NTHR) __attribute__((amdgpu_waves_per_eu(2, 2)))
void grcnn_main(
    const float* __restrict__ x, const _Float16* __restrict__ WT,
    const float* __restrict__ Wb, const float* __restrict__ Gb,
    unsigned* __restrict__ pmax, unsigned* __restrict__ brow,
    int* __restrict__ flags)
{
    __shared__ alignas(16) char lds[GBUF + 2048];   // bufA@0, bufB@BUFB, gbuf@GBUF

    const int tid = threadIdx.x;
    const int b = blockIdx.x & 31, h = blockIdx.x >> 5;
    const int w = tid >> 6, l = tid & 63, lr = l & 15, q = l >> 4;
    const int cw = w * 32;

    // ---- W fragments as NAMED scalars (guaranteed SROA -> VGPRs) ----
    const _Float16* wp0 = WT + (size_t)(cw + lr) * 512 + q * 8;
    const _Float16* wp1 = WT + (size_t)(cw + 16 + lr) * 512 + q * 8;
#define LDW(s) \
    const half8 WA##s = *(const half8*)(wp0 + s * 32); \
    const half8 WB##s = *(const half8*)(wp1 + s * 32);
    LDW(0) LDW(1) LDW(2) LDW(3) LDW(4) LDW(5) LDW(6) LDW(7)
    LDW(8) LDW(9) LDW(10) LDW(11) LDW(12) LDW(13) LDW(14) LDW(15)
#undef LDW
    // split-K gate fragments: wave w covers k-steps 2w, 2w+1
    const _Float16* wpg = WT + (size_t)(256 + lr) * 512 + q * 8;
    const half8 WG0 = *(const half8*)(wpg + (2 * w) * 32);
    const half8 WG1 = *(const half8*)(wpg + (2 * w + 1) * 32);

    // one-hot extraction frags (as B: tile0 -> S[row][cw+lr], tile1 -> +16)
    half8 oh0 = {}, oh1 = {};
    {
        _Float16 one = (_Float16)1.0f;
        #pragma unroll
        for (int j = 0; j < 8; ++j) if (j == (lr & 7)) {
            if (q == (lr >> 3))     oh0[j] = one;
            if (q == 2 + (lr >> 3)) oh1[j] = one;
        }
    }
    const float wb0 = Wb[cw + lr], wb1 = Wb[cw + 16 + lr];
    const float gbi0 = Gb[0], gbi1 = Gb[1], gbi2 = Gb[2];

    // ---- precomputed LDS addresses (bufA-relative; toggle via ^BUFB) ----
#define RDA(s) const int rd##s = SWZ(lr * 512 + s * 64 + q * 16);
    RDA(0) RDA(1) RDA(2) RDA(3) RDA(4) RDA(5) RDA(6) RDA(7)
    RDA(8) RDA(9) RDA(10) RDA(11) RDA(12) RDA(13) RDA(14) RDA(15)
#undef RDA
    const int rax  = SWZ(lr * 512 + w * 64 + q * 16);
    const int rax2 = SWZ((lr + 1) * 512 + w * 64 + q * 16);
    int wo[2][4];
    #pragma unroll
    for (int nt = 0; nt < 2; ++nt)
        #pragma unroll
        for (int r = 0; r < 4; ++r)
            wo[nt][r] = SWZ((q * 4 + r) * 512 + (cw + nt * 16 + lr) * 2);
    const int impA = 8192 + l * 8;          // row 16 (identity swizzle)
    const int gwo = GBUF + (w * 16 + lr) * 16;   // gate partial slot (conflict-free)

    int* flagP = &flags[(b * 8 + h) * 16];
    int* flagN = &flags[(b * 8 + h + 1) * 16];
    int* ackP  = &flags[(256 + b * 8 + h) * 16];
    int* ackC  = &flags[(256 + b * 8 + h - 1) * 16];
    const int slotbase = 127 * h - 8 * h * (h - 1);

    // ---- stage rows 16h..16h+16 (clamped) into BOTH buffers ----
    for (int ch = tid; ch < 17 * 32; ch += NTHR) {
        int row = ch >> 5, kc = ch & 31;
        int grow = 16 * h + row; if (grow > 127) grow = 127;
        const float* xp = x + ((size_t)b * L_ + grow) * D_ + kc * 8;
        half8 v;
        #pragma unroll
        for (int j = 0; j < 8; ++j) v[j] = (_Float16)xp[j];
        int off = SWZ(row * 512 + kc * 16);
        *(half8*)(lds + off) = v;
        *(half8*)(lds + BUFB + off) = v;
    }
    __syncthreads();

    int rb = 0;   // src base toggle; dst = rb ^ BUFB

    for (int t = 0; t < 127; ++t) {
        const int m = 127 - t - 16 * h;
        if (m <= 0) break;
        const int mm = (m > 16) ? 16 : m;
        const bool doExpN = (h >= 1) && (126 - t >= 16 * h);
        const bool doImpT = (h < 7) && (t <= 110 - 16 * h);
        const int rw = rb ^ BUFB;

        // ---- export-slot ack gate (ring depth 4), per wave, lane 0 ----
        if (doExpN && t >= 3 && l == 0) {
            while (__hip_atomic_load(ackC, __ATOMIC_RELAXED, __HIP_MEMORY_SCOPE_AGENT) < t - 3)
                __builtin_amdgcn_s_sleep(1);
        }

        // ---- MFMA: central tiles; gate split-K on this wave's 2 k-steps ----
        f32x4 a0 = {}, a1 = {}, ag = {};
#define STEP(s) { \
            half8 av = *(const half8*)(lds + (rd##s ^ rb)); \
            a0 = MFMA16(av, WA##s, a0, 0, 0, 0); \
            a1 = MFMA16(av, WB##s, a1, 0, 0, 0); \
            if ((s >> 1) == w) \
                ag = MFMA16((s & 1) ? WG1 : WG0, av, ag, 0, 0, 0); }
        STEP(0) STEP(1) STEP(2) STEP(3) STEP(4) STEP(5) STEP(6) STEP(7)
        STEP(8) STEP(9) STEP(10) STEP(11) STEP(12) STEP(13) STEP(14) STEP(15)
#undef STEP
        half8 ax  = *(const half8*)(lds + (rax  ^ rb));
        half8 ax2 = *(const half8*)(lds + (rax2 ^ rb));
        f32x4 z = {};
        f32x4 e0 = MFMA16(ax,  oh0, z, 0, 0, 0);    // lv: S[row][cw+lr]
        f32x4 e1 = MFMA16(ax,  oh1, z, 0, 0, 0);    // lv: S[row][cw+16+lr]
        f32x4 f0 = MFMA16(ax2, oh0, z, 0, 0, 0);    // rv: S[row+1][cw+lr]
        f32x4 f1 = MFMA16(ax2, oh1, z, 0, 0, 0);    // rv: S[row+1][cw+16+lr]

        // gate partial (transposed C: lane rho=l<16, regs 0..2 = gates) -> gbuf
        if (l < 16) *(f32x4*)(lds + gwo) = ag;

        __syncthreads();   // MID: gate partials visible

        // ---- deterministic gate sum + in-lane softmax (lanes 0..15) ----
        float sg0 = 0.f, sg1 = 0.f, sg2 = 0.f;
        if (l < 16) {
            float p0 = gbi0, p1 = gbi1, p2 = gbi2;
            #pragma unroll
            for (int w8 = 0; w8 < 8; ++w8) {
                f32x4 v = *(const f32x4*)(lds + GBUF + (w8 * 16 + l) * 16);
                p0 += v[0]; p1 += v[1]; p2 += v[2];
            }
            float mg = fmaxf(fmaxf(p0, p1), p2);
            float ee0 = __builtin_amdgcn_exp2f((p0 - mg) * LOG2E);
            float ee1 = __builtin_amdgcn_exp2f((p1 - mg) * LOG2E);
            float ee2 = __builtin_amdgcn_exp2f((p2 - mg) * LOG2E);
            float inv = __builtin_amdgcn_rcpf(ee0 + ee1 + ee2);
            sg0 = ee0 * inv; sg1 = ee1 * inv; sg2 = ee2 * inv;
        }

        // ---- epilogue ----
        float cm0 = -3.4e38f, cm1 = -3.4e38f;
        #pragma unroll
        for (int r = 0; r < 4; ++r) {
            const int row = q * 4 + r;
            float g0f = __shfl(sg0, row, 64);
            float g1f = __shfl(sg1, row, 64);
            float g2f = __shfl(sg2, row, 64);
            if (row < mm) {
                #define EPI(NT, ACC, EV, FV, WBV, CMV) {                                     \
                    float pre = ACC[r] + WBV;                                                \
                    float exx = __builtin_amdgcn_exp2f(pre * (2.f * LOG2E));                 \
                    float ce = 1.f - 2.f * __builtin_amdgcn_rcpf(exx + 1.f);                 \
                    float nx = g0f * EV[r] + g1f * ce + g2f * FV[r];                         \
                    CMV = fmaxf(CMV, nx);                                                    \
                    int pdi = __builtin_amdgcn_update_dpp(                                   \
                        0, __builtin_bit_cast(int, nx), 0xB1, 0xF, 0xF, true);               \
                    float pnx = __builtin_bit_cast(float, pdi);                              \
                    unsigned pk = (unsigned)__builtin_bit_cast(unsigned short, (_Float16)nx) \
                        | ((unsigned)__builtin_bit_cast(unsigned short, (_Float16)pnx) << 16);\
                    if (!(lr & 1)) {                                                         \
                        *(unsigned*)(lds + (wo[NT][r] ^ rw)) = pk;                           \
                        if (r == 0 && q == 0 && doExpN) {                                    \
                            unsigned* ep = brow +                                            \
                                (((size_t)((t + 1) & 3) * 32 + b) * 8 + h) * 128             \
                                + (cw >> 1) + NT * 8 + (lr >> 1);                            \
                            __hip_atomic_store(ep, pk, __ATOMIC_RELAXED,                     \
                                               __HIP_MEMORY_SCOPE_AGENT);                    \
                        }                                                                    \
                    }                                                                        \
                }
                EPI(0, a0, e0, f0, wb0, cm0)
                EPI(1, a1, e1, f1, wb1, cm1)
                #undef EPI
            }
        }

        // ---- col-max -> private pmax slot ----
        cm0 = fmaxf(cm0, __shfl_xor(cm0, 16, 64));
        cm0 = fmaxf(cm0, __shfl_xor(cm0, 32, 64));
        cm1 = fmaxf(cm1, __shfl_xor(cm1, 16, 64));
        cm1 = fmaxf(cm1, __shfl_xor(cm1, 32, 64));
        if (l < 16) {
            unsigned ph = (unsigned)__builtin_bit_cast(unsigned short, (_Float16)cm0)
                        | ((unsigned)__builtin_bit_cast(unsigned short, (_Float16)cm1) << 16);
            pmax[((size_t)b * PS_SLOTS + slotbase + t) * 128 + w * 16 + l] = ph;
        }

        // ---- wave 0 tail: import state-(t+1) boundary into DST row 16 ----
        if (w == 0 && doImpT) {
            if (l == 0) {
                while (__hip_atomic_load(flagN, __ATOMIC_RELAXED, __HIP_MEMORY_SCOPE_AGENT) < t + 1)
                    __builtin_amdgcn_s_sleep(1);
            }
            const unsigned long long* bp = (const unsigned long long*)brow
                + (((size_t)((t + 1) & 3) * 32 + b) * 8 + (h + 1)) * 64 + l;
            unsigned long long iv =
                __hip_atomic_load(bp, __ATOMIC_RELAXED, __HIP_MEMORY_SCOPE_AGENT);
            *(unsigned long long*)(lds + (impA ^ rw)) = iv;
            if (l == 0)
                __hip_atomic_store(ackP, t + 1, __ATOMIC_RELAXED, __HIP_MEMORY_SCOPE_AGENT);
        }

        __syncthreads();   // END: dst rows + import + exports drained

        if (tid == 0 && doExpN)
            __hip_atomic_store(flagP, t + 1, __ATOMIC_RELAXED, __HIP_MEMORY_SCOPE_AGENT);
        rb ^= BUFB;
    }
}

extern "C" void kernel_launch(void* const* d_in, const int* in_sizes, int n_in,
                              void* d_out, int out_size, void* d_ws, size_t ws_size,
                              hipStream_t stream) {
    const float* x  = (const float*)d_in[0];
    const float* Wl = (const float*)d_in[1];
    const float* Wr = (const float*)d_in[2];
    const float* Wb = (const float*)d_in[3];
    const float* Gl = (const float*)d_in[4];
    const float* Gr = (const float*)d_in[5];
    const float* Gb = (const float*)d_in[6];
    float* out = (float*)d_out;
    char* ws = (char*)d_ws;

    _Float16* WT = (_Float16*)ws;                         // 278,528 B
    unsigned* brow = (unsigned*)(ws + 278528);            // 524,288 B (ring 4)
    int* flags = (int*)(ws + 802816);                     // 32,768 B
    unsigned* pmax = (unsigned*)(ws + 835584);            // 9,306,112 B

    prep_wt<<<272, 256, 0, stream>>>(Wl, Wr, Gl, Gr, WT);
    init_misc<<<B_, 256, 0, stream>>>(x, out, flags);

    void* args[] = { (void*)&x, (void*)&WT, (void*)&Wb, (void*)&Gb,
                     (void*)&pmax, (void*)&brow, (void*)&flags };
    hipLaunchCooperativeKernel((const void*)grcnn_main, dim3(B_ * 8), dim3(NTHR),
                               args, 0, stream);

    decode_out<<<1024, 256, 0, stream>>>(pmax, out);
}

// Round 13
// 462.700 us; speedup vs baseline: 1.4717x; 1.1270x over previous
//
#include <hip/hip_runtime.h>

// GrCNN: B=32, L=128, D=256, 127 sequential levels.
// Round 13: row-slab (256 blocks=(b,h), 16 rows, 8 waves x 32 cols).
// = Round 10 (passed, 521us) + W pinned via 32-bit component pins, with the
// working set SLIMMED so pinned-W + live regs fit under 256 VGPRs:
//  - one-hot extraction machinery DELETED (oh/ax/ax2/e0/e1/f0/f1: ~40 VGPRs,
//    4 MFMAs); lv/rv = 10 direct ds_read_u16 (rows q*4..q*4+4, 2 cols) --
//    bit-identical fp16 values, so numerics unchanged.
//  - WG gate frags unpinned (128B/level restream is negligible).
//  - __launch_bounds__(512,2): hard 256 cap -> spills rather than becoming
//    unlaunchable (rounds 11/12 silently failed to launch: VGPR>256 with
//    512-thread blocks; identical absmax 3.94 = decode of poisoned pmax).
// Gates split-K across waves (LDS partial sum, MID bar). Protocol (ring-4
// flag/ack, tail import into dst row16, reg-export, pmax+decode) = rounds 8-10.

#define B_ 32
#define L_ 128
#define D_ 256
#define NTHR 512
#define BUFB 16384
#define GBUF 25088            // gbuf: [w][16] f32x4 = 2048 B
#define LOG2E 1.4426950408889634f
#define PS_SLOTS 568          // sum_{h=0}^{7} (127-16h)

typedef _Float16 half8 __attribute__((ext_vector_type(8)));
typedef float f32x4 __attribute__((ext_vector_type(4)));
typedef unsigned u32x4 __attribute__((ext_vector_type(4)));

#define SWZ(o)  ((o) ^ ((((o) >> 9) & 7) << 4))
#define MFMA16 __builtin_amdgcn_mfma_f32_16x16x32_f16

// 32-bit-component register pin: value becomes opaque to remat, stays in VGPRs.
#define PIN(H) { \
    u32x4 t_ = __builtin_bit_cast(u32x4, H); \
    unsigned p0_ = t_[0], p1_ = t_[1], p2_ = t_[2], p3_ = t_[3]; \
    asm volatile("" : "+v"(p0_), "+v"(p1_), "+v"(p2_), "+v"(p3_)); \
    t_[0] = p0_; t_[1] = p1_; t_[2] = p2_; t_[3] = p3_; \
    H = __builtin_bit_cast(half8, t_); }

// ---- WT[272][512] fp16: col j -> 512 k (k<256: Wl/Gl row k, else Wr/Gr) ----
__global__ void prep_wt(const float* __restrict__ Wl, const float* __restrict__ Wr,
                        const float* __restrict__ Gl, const float* __restrict__ Gr,
                        _Float16* __restrict__ WT) {
    int j = blockIdx.x;
    for (int k = threadIdx.x; k < 512; k += 256) {
        float v = 0.f;
        if (j < 256) v = (k < 256) ? Wl[k * 256 + j] : Wr[(k - 256) * 256 + j];
        else { int jj = j - 256; if (jj < 3) v = (k < 256) ? Gl[k * 3 + jj] : Gr[(k - 256) * 3 + jj]; }
        WT[(size_t)j * 512 + k] = (_Float16)v;
    }
}

// ---- init: zero flags+acks, level-0 col max ----
__global__ void init_misc(const float* __restrict__ x, float* __restrict__ out,
                          int* __restrict__ flags) {
    int b = blockIdx.x, c = threadIdx.x;
    if (b == 0) for (int i = c; i < 2 * 256 * 16; i += 256) flags[i] = 0;
    float m = -3.4e38f;
    for (int row = 0; row < L_; ++row)
        m = fmaxf(m, x[((size_t)b * L_ + row) * D_ + c]);
    out[(size_t)b * L_ * D_ + c] = m;
}

// ---- decode: pmax (fp16-packed partials per (b,slot)) -> out levels 1..127 ----
__global__ void decode_out(const unsigned* __restrict__ pmax, float* __restrict__ out) {
    for (size_t i = (size_t)blockIdx.x * 256 + threadIdx.x; i < (size_t)32 * 127 * 256;
         i += (size_t)gridDim.x * 256) {
        int c = (int)(i & 255);
        int k = (int)((i >> 8) % 127) + 1;
        int b = (int)(i / (127 * 256));
        int hcnt = (143 - k) >> 4;              // ceil((128-k)/16)
        int dw = ((c >> 5) * 16) + (c & 15);
        int hi = (c >> 4) & 1;
        float mx = -3.4e38f;
        for (int h = 0; h < hcnt; ++h) {
            int slot = 127 * h - 8 * h * (h - 1) + (k - 1);
            unsigned u = pmax[((size_t)b * PS_SLOTS + slot) * 128 + dw];
            unsigned short us = hi ? (unsigned short)(u >> 16) : (unsigned short)(u & 0xffff);
            float v = (float)__builtin_bit_cast(_Float16, us);
            mx = fmaxf(mx, v);
        }
        out[((size_t)b * 128 + k) * 256 + c] = mx;
    }
}

__global__ __launch_bounds__(NTHR, 2) void grcnn_main(
    const float* __restrict__ x, const _Float16* __restrict__ WT,
    const float* __restrict__ Wb, const float* __restrict__ Gb,
    unsigned* __restrict__ pmax, unsigned* __restrict__ brow,
    int* __restrict__ flags)
{
    __shared__ alignas(16) char lds[GBUF + 2048];   // bufA@0, bufB@BUFB, gbuf@GBUF

    const int tid = threadIdx.x;
    const int b = blockIdx.x & 31, h = blockIdx.x >> 5;
    const int w = tid >> 6, l = tid & 63, lr = l & 15, q = l >> 4;
    const int cw = w * 32;

    // ---- W fragments -> VGPRs, pinned via 32-bit components ----
    const _Float16* wp0 = WT + (size_t)(cw + lr) * 512 + q * 8;
    const _Float16* wp1 = WT + (size_t)(cw + 16 + lr) * 512 + q * 8;
#define LDW(s) \
    half8 WA##s = *(const half8*)(wp0 + s * 32); \
    half8 WB##s = *(const half8*)(wp1 + s * 32); \
    PIN(WA##s) PIN(WB##s)
    LDW(0) LDW(1) LDW(2) LDW(3) LDW(4) LDW(5) LDW(6) LDW(7)
    LDW(8) LDW(9) LDW(10) LDW(11) LDW(12) LDW(13) LDW(14) LDW(15)
#undef LDW
    // split-K gate fragments (UNPINNED -- restream is 128B/level, negligible)
    const _Float16* wpg = WT + (size_t)(256 + lr) * 512 + q * 8;
    const half8 WG0 = *(const half8*)(wpg + (2 * w) * 32);
    const half8 WG1 = *(const half8*)(wpg + (2 * w + 1) * 32);

    const float wb0 = Wb[cw + lr], wb1 = Wb[cw + 16 + lr];
    const float gbi0 = Gb[0], gbi1 = Gb[1], gbi2 = Gb[2];

    // ---- precomputed LDS addresses (bufA-relative; toggle via ^rb) ----
#define RDA(s) const int rd##s = SWZ(lr * 512 + s * 64 + q * 16);
    RDA(0) RDA(1) RDA(2) RDA(3) RDA(4) RDA(5) RDA(6) RDA(7)
    RDA(8) RDA(9) RDA(10) RDA(11) RDA(12) RDA(13) RDA(14) RDA(15)
#undef RDA
    int wo[2][4];
    #pragma unroll
    for (int nt = 0; nt < 2; ++nt)
        #pragma unroll
        for (int r = 0; r < 4; ++r)
            wo[nt][r] = SWZ((q * 4 + r) * 512 + (cw + nt * 16 + lr) * 2);
    // lv/rv scalar-read addresses: rows q*4 .. q*4+4 at the two owned cols
    int lvo0[5], lvo1[5];
    #pragma unroll
    for (int i = 0; i < 5; ++i) {
        lvo0[i] = SWZ((q * 4 + i) * 512 + (cw + lr) * 2);
        lvo1[i] = SWZ((q * 4 + i) * 512 + (cw + 16 + lr) * 2);
    }
    const int impA = 8192 + l * 8;          // row 16 (identity swizzle)
    const int gwo = GBUF + (w * 16 + lr) * 16;   // gate partial slot (conflict-free)

    int* flagP = &flags[(b * 8 + h) * 16];
    int* flagN = &flags[(b * 8 + h + 1) * 16];
    int* ackP  = &flags[(256 + b * 8 + h) * 16];
    int* ackC  = &flags[(256 + b * 8 + h - 1) * 16];
    const int slotbase = 127 * h - 8 * h * (h - 1);

    // ---- stage rows 16h..16h+16 (clamped) into BOTH buffers ----
    for (int ch = tid; ch < 17 * 32; ch += NTHR) {
        int row = ch >> 5, kc = ch & 31;
        int grow = 16 * h + row; if (grow > 127) grow = 127;
        const float* xp = x + ((size_t)b * L_ + grow) * D_ + kc * 8;
        half8 v;
        #pragma unroll
        for (int j = 0; j < 8; ++j) v[j] = (_Float16)xp[j];
        int off = SWZ(row * 512 + kc * 16);
        *(half8*)(lds + off) = v;
        *(half8*)(lds + BUFB + off) = v;
    }
    __syncthreads();

    int rb = 0;   // src base toggle; dst = rb ^ BUFB

    for (int t = 0; t < 127; ++t) {
        const int m = 127 - t - 16 * h;
        if (m <= 0) break;
        const int mm = (m > 16) ? 16 : m;
        const bool doExpN = (h >= 1) && (126 - t >= 16 * h);
        const bool doImpT = (h < 7) && (t <= 110 - 16 * h);
        const int rw = rb ^ BUFB;

        // ---- export-slot ack gate (ring depth 4), per wave, lane 0 ----
        if (doExpN && t >= 3 && l == 0) {
            while (__hip_atomic_load(ackC, __ATOMIC_RELAXED, __HIP_MEMORY_SCOPE_AGENT) < t - 3)
                __builtin_amdgcn_s_sleep(1);
        }

        // ---- MFMA: central tiles; gate split-K on this wave's 2 k-steps ----
        f32x4 a0 = {}, a1 = {}, ag = {};
#define STEP(s) { \
            half8 av = *(const half8*)(lds + (rd##s ^ rb)); \
            a0 = MFMA16(av, WA##s, a0, 0, 0, 0); \
            a1 = MFMA16(av, WB##s, a1, 0, 0, 0); \
            if ((s >> 1) == w) \
                ag = MFMA16((s & 1) ? WG1 : WG0, av, ag, 0, 0, 0); }
        STEP(0) STEP(1) STEP(2) STEP(3) STEP(4) STEP(5) STEP(6) STEP(7)
        STEP(8) STEP(9) STEP(10) STEP(11) STEP(12) STEP(13) STEP(14) STEP(15)
#undef STEP

        // ---- lv/rv direct LDS reads (src stable all level) ----
        float v0[5], v1[5];
        #pragma unroll
        for (int i = 0; i < 5; ++i) {
            v0[i] = (float)*(const _Float16*)(lds + (lvo0[i] ^ rb));
            v1[i] = (float)*(const _Float16*)(lds + (lvo1[i] ^ rb));
        }

        // gate partial (transposed C: lane rho=l<16, regs 0..2 = gates) -> gbuf
        if (l < 16) *(f32x4*)(lds + gwo) = ag;

        __syncthreads();   // MID: gate partials visible

        // ---- deterministic gate sum + in-lane softmax (lanes 0..15) ----
        float sg0 = 0.f, sg1 = 0.f, sg2 = 0.f;
        if (l < 16) {
            float p0 = gbi0, p1 = gbi1, p2 = gbi2;
            #pragma unroll
            for (int w8 = 0; w8 < 8; ++w8) {
                f32x4 v = *(const f32x4*)(lds + GBUF + (w8 * 16 + l) * 16);
                p0 += v[0]; p1 += v[1]; p2 += v[2];
            }
            float mg = fmaxf(fmaxf(p0, p1), p2);
            float ee0 = __builtin_amdgcn_exp2f((p0 - mg) * LOG2E);
            float ee1 = __builtin_amdgcn_exp2f((p1 - mg) * LOG2E);
            float ee2 = __builtin_amdgcn_exp2f((p2 - mg) * LOG2E);
            float inv = __builtin_amdgcn_rcpf(ee0 + ee1 + ee2);
            sg0 = ee0 * inv; sg1 = ee1 * inv; sg2 = ee2 * inv;
        }

        // ---- epilogue ----
        float cm0 = -3.4e38f, cm1 = -3.4e38f;
        #pragma unroll
        for (int r = 0; r < 4; ++r) {
            const int row = q * 4 + r;
            float g0f = __shfl(sg0, row, 64);
            float g1f = __shfl(sg1, row, 64);
            float g2f = __shfl(sg2, row, 64);
            if (row < mm) {
                #define EPI(NT, ACC, LV, RV, WBV, CMV) {                                     \
                    float pre = ACC[r] + WBV;                                                \
                    float exx = __builtin_amdgcn_exp2f(pre * (2.f * LOG2E));                 \
                    float ce = 1.f - 2.f * __builtin_amdgcn_rcpf(exx + 1.f);                 \
                    float nx = g0f * (LV) + g1f * ce + g2f * (RV);                           \
                    CMV = fmaxf(CMV, nx);                                                    \
                    int pdi = __builtin_amdgcn_update_dpp(                                   \
                        0, __builtin_bit_cast(int, nx), 0xB1, 0xF, 0xF, true);               \
                    float pnx = __builtin_bit_cast(float, pdi);                              \
                    unsigned pk = (unsigned)__builtin_bit_cast(unsigned short, (_Float16)nx) \
                        | ((unsigned)__builtin_bit_cast(unsigned short, (_Float16)pnx) << 16);\
                    if (!(lr & 1)) {                                                         \
                        *(unsigned*)(lds + (wo[NT][r] ^ rw)) = pk;                           \
                        if (r == 0 && q == 0 && doExpN) {                                    \
                            unsigned* ep = brow +                                            \
                                (((size_t)((t + 1) & 3) * 32 + b) * 8 + h) * 128             \
                                + (cw >> 1) + NT * 8 + (lr >> 1);                            \
                            __hip_atomic_store(ep, pk, __ATOMIC_RELAXED,                     \
                                               __HIP_MEMORY_SCOPE_AGENT);                    \
                        }                                                                    \
                    }                                                                        \
                }
                EPI(0, a0, v0[r], v0[r + 1], wb0, cm0)
                EPI(1, a1, v1[r], v1[r + 1], wb1, cm1)
                #undef EPI
            }
        }

        // ---- col-max -> private pmax slot ----
        cm0 = fmaxf(cm0, __shfl_xor(cm0, 16, 64));
        cm0 = fmaxf(cm0, __shfl_xor(cm0, 32, 64));
        cm1 = fmaxf(cm1, __shfl_xor(cm1, 16, 64));
        cm1 = fmaxf(cm1, __shfl_xor(cm1, 32, 64));
        if (l < 16) {
            unsigned ph = (unsigned)__builtin_bit_cast(unsigned short, (_Float16)cm0)
                        | ((unsigned)__builtin_bit_cast(unsigned short, (_Float16)cm1) << 16);
            pmax[((size_t)b * PS_SLOTS + slotbase + t) * 128 + w * 16 + l] = ph;
        }

        // ---- wave 0 tail: import state-(t+1) boundary into DST row 16 ----
        if (w == 0 && doImpT) {
            if (l == 0) {
                while (__hip_atomic_load(flagN, __ATOMIC_RELAXED, __HIP_MEMORY_SCOPE_AGENT) < t + 1)
                    __builtin_amdgcn_s_sleep(1);
            }
            const unsigned long long* bp = (const unsigned long long*)brow
                + (((size_t)((t + 1) & 3) * 32 + b) * 8 + (h + 1)) * 64 + l;
            unsigned long long iv =
                __hip_atomic_load(bp, __ATOMIC_RELAXED, __HIP_MEMORY_SCOPE_AGENT);
            *(unsigned long long*)(lds + (impA ^ rw)) = iv;
            if (l == 0)
                __hip_atomic_store(ackP, t + 1, __ATOMIC_RELAXED, __HIP_MEMORY_SCOPE_AGENT);
        }

        __syncthreads();   // END: dst rows + import + exports drained

        if (tid == 0 && doExpN)
            __hip_atomic_store(flagP, t + 1, __ATOMIC_RELAXED, __HIP_MEMORY_SCOPE_AGENT);
        rb ^= BUFB;
    }
}

extern "C" void kernel_launch(void* const* d_in, const int* in_sizes, int n_in,
                              void* d_out, int out_size, void* d_ws, size_t ws_size,
                              hipStream_t stream) {
    const float* x  = (const float*)d_in[0];
    const float* Wl = (const float*)d_in[1];
    const float* Wr = (const float*)d_in[2];
    const float* Wb = (const float*)d_in[3];
    const float* Gl = (const float*)d_in[4];
    const float* Gr = (const float*)d_in[5];
    const float* Gb = (const float*)d_in[6];
    float* out = (float*)d_out;
    char* ws = (char*)d_ws;

    _Float16* WT = (_Float16*)ws;                         // 278,528 B
    unsigned* brow = (unsigned*)(ws + 278528);            // 524,288 B (ring 4)
    int* flags = (int*)(ws + 802816);                     // 32,768 B
    unsigned* pmax = (unsigned*)(ws + 835584);            // 9,306,112 B

    prep_wt<<<272, 256, 0, stream>>>(Wl, Wr, Gl, Gr, WT);
    init_misc<<<B_, 256, 0, stream>>>(x, out, flags);

    void* args[] = { (void*)&x, (void*)&WT, (void*)&Wb, (void*)&Gb,
                     (void*)&pmax, (void*)&brow, (void*)&flags };
    hipLaunchCooperativeKernel((const void*)grcnn_main, dim3(B_ * 8), dim3(NTHR),
                               args, 0, stream);

    decode_out<<<1024, 256, 0, stream>>>(pmax, out);
}

// Round 15
// 442.062 us; speedup vs baseline: 1.5404x; 1.0467x over previous
//
#include <hip/hip_runtime.h>

// GrCNN: B=32, L=128, D=256, 127 sequential levels.
// Round 15: = round 14 (K-split pairing + carried lv/rv) with carries kept in
// FULL FP32 (r14 rounded the carry to fp16 each level; that per-cell
// per-level rounding dominated the 127-level error walk and landed 10% over
// threshold). With fp32 carries the only fp16 roundings left in the state
// evolution are MFMA inputs (tanh-compressed) and the 7 slab-boundary rows
// -> ~18x fewer injection sites, restoring margin for the K-split reassoc.
//  - K-SPLIT PAIRING: wave (g=w&3, khalf=w>>2) reads only its K-half
//    (8 b128) and computes 4-tile partials for colgroup [64g,64g+64);
//    pair exchanges 2 tiles via LDS at the existing MID barrier; wave
//    epilogues cols cw=64g+32*khalf. Gate split-K folded into its half.
//  - W pinned via 32-bit pins (lands in AGPRs, r13-verified).
// Ring-4 flag/ack, tail import to dst row16, reg-export, pmax+decode = r8-r14.

#define B_ 32
#define L_ 128
#define D_ 256
#define NTHR 512
#define BUFB 16384
#define GBUF 25088            // gbuf: [w][16] f32x4 = 2048 B
#define PEX  27136            // pexch: [g][tile][lane] f32x4 = 16384 B
#define LOG2E 1.4426950408889634f
#define PS_SLOTS 568          // sum_{h=0}^{7} (127-16h)

typedef _Float16 half8 __attribute__((ext_vector_type(8)));
typedef float f32x4 __attribute__((ext_vector_type(4)));
typedef unsigned u32x4 __attribute__((ext_vector_type(4)));

#define SWZ(o)  ((o) ^ ((((o) >> 9) & 7) << 4))
#define MFMA16 __builtin_amdgcn_mfma_f32_16x16x32_f16

// 32-bit-component register pin (r13-verified: stays resident, no remat)
#define PIN(H) { \
    u32x4 t_ = __builtin_bit_cast(u32x4, H); \
    unsigned p0_ = t_[0], p1_ = t_[1], p2_ = t_[2], p3_ = t_[3]; \
    asm volatile("" : "+v"(p0_), "+v"(p1_), "+v"(p2_), "+v"(p3_)); \
    t_[0] = p0_; t_[1] = p1_; t_[2] = p2_; t_[3] = p3_; \
    H = __builtin_bit_cast(half8, t_); }

// ---- WT[272][512] fp16: col j -> 512 k (k<256: Wl/Gl row k, else Wr/Gr) ----
__global__ void prep_wt(const float* __restrict__ Wl, const float* __restrict__ Wr,
                        const float* __restrict__ Gl, const float* __restrict__ Gr,
                        _Float16* __restrict__ WT) {
    int j = blockIdx.x;
    for (int k = threadIdx.x; k < 512; k += 256) {
        float v = 0.f;
        if (j < 256) v = (k < 256) ? Wl[k * 256 + j] : Wr[(k - 256) * 256 + j];
        else { int jj = j - 256; if (jj < 3) v = (k < 256) ? Gl[k * 3 + jj] : Gr[(k - 256) * 3 + jj]; }
        WT[(size_t)j * 512 + k] = (_Float16)v;
    }
}

// ---- init: zero flags+acks, level-0 col max ----
__global__ void init_misc(const float* __restrict__ x, float* __restrict__ out,
                          int* __restrict__ flags) {
    int b = blockIdx.x, c = threadIdx.x;
    if (b == 0) for (int i = c; i < 2 * 256 * 16; i += 256) flags[i] = 0;
    float m = -3.4e38f;
    for (int row = 0; row < L_; ++row)
        m = fmaxf(m, x[((size_t)b * L_ + row) * D_ + c]);
    out[(size_t)b * L_ * D_ + c] = m;
}

// ---- decode: pmax partials -> out levels 1..127 (col map for K-split waves) ----
__global__ void decode_out(const unsigned* __restrict__ pmax, float* __restrict__ out) {
    for (size_t i = (size_t)blockIdx.x * 256 + threadIdx.x; i < (size_t)32 * 127 * 256;
         i += (size_t)gridDim.x * 256) {
        int c = (int)(i & 255);
        int k = (int)((i >> 8) % 127) + 1;
        int b = (int)(i / (127 * 256));
        int hcnt = (143 - k) >> 4;              // ceil((128-k)/16)
        // c = 64g + 32khalf + 16NT + lr; w = 4khalf+g; dw = w*16+lr
        int dw = ((c >> 5) & 1) * 64 + ((c >> 6) & 3) * 16 + (c & 15);
        int hi = (c >> 4) & 1;                  // NT
        float mx = -3.4e38f;
        for (int h = 0; h < hcnt; ++h) {
            int slot = 127 * h - 8 * h * (h - 1) + (k - 1);
            unsigned u = pmax[((size_t)b * PS_SLOTS + slot) * 128 + dw];
            unsigned short us = hi ? (unsigned short)(u >> 16) : (unsigned short)(u & 0xffff);
            float v = (float)__builtin_bit_cast(_Float16, us);
            mx = fmaxf(mx, v);
        }
        out[((size_t)b * 128 + k) * 256 + c] = mx;
    }
}

__global__ __launch_bounds__(NTHR, 2) void grcnn_main(
    const float* __restrict__ x, const _Float16* __restrict__ WT,
    const float* __restrict__ Wb, const float* __restrict__ Gb,
    unsigned* __restrict__ pmax, unsigned* __restrict__ brow,
    int* __restrict__ flags)
{
    __shared__ alignas(16) char lds[PEX + 16384];  // bufA@0, bufB@BUFB, gbuf, pexch

    const int tid = threadIdx.x;
    const int b = blockIdx.x & 31, h = blockIdx.x >> 5;
    const int w = tid >> 6, l = tid & 63, lr = l & 15, q = l >> 4;
    const int g = w & 3, khalf = w >> 2;
    const int cw = g * 64 + khalf * 32;     // wave's epilogue 32-col slab

    // ---- W fragments: 4 tiles x 8 ksteps of this wave's K-half, pinned ----
    const _Float16* wtb0 = WT + (size_t)(64 * g + lr) * 512 + khalf * 256 + q * 8;
    const _Float16* wtb1 = WT + (size_t)(64 * g + 16 + lr) * 512 + khalf * 256 + q * 8;
    const _Float16* wtb2 = WT + (size_t)(64 * g + 32 + lr) * 512 + khalf * 256 + q * 8;
    const _Float16* wtb3 = WT + (size_t)(64 * g + 48 + lr) * 512 + khalf * 256 + q * 8;
#define LDW1(T, i) half8 W##T##_##i = *(const half8*)(wtb##T + i * 32); PIN(W##T##_##i)
#define LDWT(T) LDW1(T,0) LDW1(T,1) LDW1(T,2) LDW1(T,3) LDW1(T,4) LDW1(T,5) LDW1(T,6) LDW1(T,7)
    LDWT(0) LDWT(1) LDWT(2) LDWT(3)
#undef LDWT
#undef LDW1
    // gate frags: global ksteps 8*khalf + {2g, 2g+1} (union over waves = all 16)
    const _Float16* wpg = WT + (size_t)(256 + lr) * 512 + q * 8;
    const half8 WG0 = *(const half8*)(wpg + (8 * khalf + 2 * g) * 32);
    const half8 WG1 = *(const half8*)(wpg + (8 * khalf + 2 * g + 1) * 32);

    const float wb0 = Wb[cw + lr], wb1 = Wb[cw + 16 + lr];
    const float gbi0 = Gb[0], gbi1 = Gb[1], gbi2 = Gb[2];

    // ---- precomputed LDS addresses ----
#define RDA(i) const int rd##i = SWZ(lr * 512 + (8 * khalf + i) * 64 + q * 16);
    RDA(0) RDA(1) RDA(2) RDA(3) RDA(4) RDA(5) RDA(6) RDA(7)
#undef RDA
    int wo[2][4];
    #pragma unroll
    for (int nt = 0; nt < 2; ++nt)
        #pragma unroll
        for (int r = 0; r < 4; ++r)
            wo[nt][r] = SWZ((q * 4 + r) * 512 + (cw + nt * 16 + lr) * 2);
    const int impA = 8192 + l * 8;               // row 16 (identity swizzle)
    const int bnd0 = 8192 + (cw + lr) * 2;       // boundary u16 (identity swizzle)
    const int bnd1 = 8192 + (cw + 16 + lr) * 2;
    const int gwo = GBUF + (w * 16 + lr) * 16;   // gate partial slot
#define PSLOT(T) (PEX + (((g * 4 + (T)) * 64 + l) * 16))

    int* flagP = &flags[(b * 8 + h) * 16];
    int* flagN = &flags[(b * 8 + h + 1) * 16];
    int* ackP  = &flags[(256 + b * 8 + h) * 16];
    int* ackC  = &flags[(256 + b * 8 + h - 1) * 16];
    const int slotbase = 127 * h - 8 * h * (h - 1);

    // ---- stage rows 16h..16h+16 (clamped) into BOTH buffers ----
    for (int ch = tid; ch < 17 * 32; ch += NTHR) {
        int row = ch >> 5, kc = ch & 31;
        int grow = 16 * h + row; if (grow > 127) grow = 127;
        const float* xp = x + ((size_t)b * L_ + grow) * D_ + kc * 8;
        half8 v;
        #pragma unroll
        for (int j = 0; j < 8; ++j) v[j] = (_Float16)xp[j];
        int off = SWZ(row * 512 + kc * 16);
        *(half8*)(lds + off) = v;
        *(half8*)(lds + BUFB + off) = v;
    }
    __syncthreads();

    // ---- init lv/rv carries from staged state (rows q*4..q*4+3, 2 cols) ----
    float cv0[4], cv1[4];
    #pragma unroll
    for (int i = 0; i < 4; ++i) {
        cv0[i] = (float)*(const _Float16*)(lds + SWZ((q * 4 + i) * 512 + (cw + lr) * 2));
        cv1[i] = (float)*(const _Float16*)(lds + SWZ((q * 4 + i) * 512 + (cw + 16 + lr) * 2));
    }

    int rb = 0;   // src base toggle; dst = rb ^ BUFB

    for (int t = 0; t < 127; ++t) {
        const int m = 127 - t - 16 * h;
        if (m <= 0) break;
        const int mm = (m > 16) ? 16 : m;
        const bool doExpN = (h >= 1) && (126 - t >= 16 * h);
        const bool doImpT = (h < 7) && (t <= 110 - 16 * h);
        const int rw = rb ^ BUFB;

        // ---- export-slot ack gate (ring depth 4), per wave, lane 0 ----
        if (doExpN && t >= 3 && l == 0) {
            while (__hip_atomic_load(ackC, __ATOMIC_RELAXED, __HIP_MEMORY_SCOPE_AGENT) < t - 3)
                __builtin_amdgcn_s_sleep(1);
        }

        // ---- MFMA: 4-tile partials over this wave's K-half + gate split-K ----
        f32x4 p0 = {}, p1 = {}, p2 = {}, p3 = {}, ag = {};
#define STEP(i) { \
            half8 av = *(const half8*)(lds + (rd##i ^ rb)); \
            p0 = MFMA16(av, W0_##i, p0, 0, 0, 0); \
            p1 = MFMA16(av, W1_##i, p1, 0, 0, 0); \
            p2 = MFMA16(av, W2_##i, p2, 0, 0, 0); \
            p3 = MFMA16(av, W3_##i, p3, 0, 0, 0); \
            if ((i >> 1) == g) \
                ag = MFMA16((i & 1) ? WG1 : WG0, av, ag, 0, 0, 0); }
        STEP(0) STEP(1) STEP(2) STEP(3) STEP(4) STEP(5) STEP(6) STEP(7)
#undef STEP

        // ---- write partner's 2 tiles + gate partial -> LDS ----
        if (khalf == 0) {
            *(f32x4*)(lds + PSLOT(2)) = p2;
            *(f32x4*)(lds + PSLOT(3)) = p3;
        } else {
            *(f32x4*)(lds + PSLOT(0)) = p0;
            *(f32x4*)(lds + PSLOT(1)) = p1;
        }
        if (l < 16) *(f32x4*)(lds + gwo) = ag;

        __syncthreads();   // MID: partials + gate partials visible

        // ---- combine own-tile partials ----
        f32x4 a0, a1;
        if (khalf == 0) {
            a0 = p0 + *(const f32x4*)(lds + PSLOT(0));
            a1 = p1 + *(const f32x4*)(lds + PSLOT(1));
        } else {
            a0 = p2 + *(const f32x4*)(lds + PSLOT(2));
            a1 = p3 + *(const f32x4*)(lds + PSLOT(3));
        }

        // ---- deterministic gate sum + in-lane softmax (lanes 0..15) ----
        float sg0 = 0.f, sg1 = 0.f, sg2 = 0.f;
        if (l < 16) {
            float s0g = gbi0, s1g = gbi1, s2g = gbi2;
            #pragma unroll
            for (int w8 = 0; w8 < 8; ++w8) {
                f32x4 v = *(const f32x4*)(lds + GBUF + (w8 * 16 + l) * 16);
                s0g += v[0]; s1g += v[1]; s2g += v[2];
            }
            float mg = fmaxf(fmaxf(s0g, s1g), s2g);
            float ee0 = __builtin_amdgcn_exp2f((s0g - mg) * LOG2E);
            float ee1 = __builtin_amdgcn_exp2f((s1g - mg) * LOG2E);
            float ee2 = __builtin_amdgcn_exp2f((s2g - mg) * LOG2E);
            float inv = __builtin_amdgcn_rcpf(ee0 + ee1 + ee2);
            sg0 = ee0 * inv; sg1 = ee1 * inv; sg2 = ee2 * inv;
        }

        // ---- boundary rv (row 16, fp16) + next-q-group row-0 carry (fp32) ----
        float b0 = (float)*(const _Float16*)(lds + (bnd0 ^ rb));
        float b1 = (float)*(const _Float16*)(lds + (bnd1 ^ rb));
        float s0 = __shfl(cv0[0], (l + 16) & 63, 64);
        float s1 = __shfl(cv1[0], (l + 16) & 63, 64);

        // ---- epilogue ----
        float cm0 = -3.4e38f, cm1 = -3.4e38f;
        #pragma unroll
        for (int r = 0; r < 4; ++r) {
            const int row = q * 4 + r;
            float g0f = __shfl(sg0, row, 64);
            float g1f = __shfl(sg1, row, 64);
            float g2f = __shfl(sg2, row, 64);
            if (row < mm) {
                #define EPI(NT, ACC, CV, SHV, BV, WBV, CMV) {                                \
                    float pre = ACC[r] + WBV;                                                \
                    float exx = __builtin_amdgcn_exp2f(pre * (2.f * LOG2E));                 \
                    float ce = 1.f - 2.f * __builtin_amdgcn_rcpf(exx + 1.f);                 \
                    float lv = CV[r];                                                        \
                    float rv = (r < 3) ? CV[(r < 3) ? r + 1 : 0] : (q < 3 ? SHV : BV);       \
                    float nx = g0f * lv + g1f * ce + g2f * rv;                               \
                    CMV = fmaxf(CMV, nx);                                                    \
                    _Float16 nh = (_Float16)nx;                                              \
                    CV[r] = nx;   /* FP32 carry: no per-level rounding */                    \
                    int pdi = __builtin_amdgcn_update_dpp(                                   \
                        0, __builtin_bit_cast(int, nx), 0xB1, 0xF, 0xF, true);               \
                    float pnx = __builtin_bit_cast(float, pdi);                              \
                    unsigned pk = (unsigned)__builtin_bit_cast(unsigned short, nh)           \
                        | ((unsigned)__builtin_bit_cast(unsigned short, (_Float16)pnx) << 16);\
                    if (!(lr & 1)) {                                                         \
                        *(unsigned*)(lds + (wo[NT][r] ^ rw)) = pk;                           \
                        if (r == 0 && q == 0 && doExpN) {                                    \
                            unsigned* ep = brow +                                            \
                                (((size_t)((t + 1) & 3) * 32 + b) * 8 + h) * 128             \
                                + (cw >> 1) + NT * 8 + (lr >> 1);                            \
                            __hip_atomic_store(ep, pk, __ATOMIC_RELAXED,                     \
                                               __HIP_MEMORY_SCOPE_AGENT);                    \
                        }                                                                    \
                    }                                                                        \
                }
                EPI(0, a0, cv0, s0, b0, wb0, cm0)
                EPI(1, a1, cv1, s1, b1, wb1, cm1)
                #undef EPI
            }
        }

        // ---- col-max -> private pmax slot ----
        cm0 = fmaxf(cm0, __shfl_xor(cm0, 16, 64));
        cm0 = fmaxf(cm0, __shfl_xor(cm0, 32, 64));
        cm1 = fmaxf(cm1, __shfl_xor(cm1, 16, 64));
        cm1 = fmaxf(cm1, __shfl_xor(cm1, 32, 64));
        if (l < 16) {
            unsigned ph = (unsigned)__builtin_bit_cast(unsigned short, (_Float16)cm0)
                        | ((unsigned)__builtin_bit_cast(unsigned short, (_Float16)cm1) << 16);
            pmax[((size_t)b * PS_SLOTS + slotbase + t) * 128 + w * 16 + l] = ph;
        }

        // ---- wave 0 tail: import state-(t+1) boundary into DST row 16 ----
        if (w == 0 && doImpT) {
            if (l == 0) {
                while (__hip_atomic_load(flagN, __ATOMIC_RELAXED, __HIP_MEMORY_SCOPE_AGENT) < t + 1)
                    __builtin_amdgcn_s_sleep(1);
            }
            const unsigned long long* bp = (const unsigned long long*)brow
                + (((size_t)((t + 1) & 3) * 32 + b) * 8 + (h + 1)) * 64 + l;
            unsigned long long iv =
                __hip_atomic_load(bp, __ATOMIC_RELAXED, __HIP_MEMORY_SCOPE_AGENT);
            *(unsigned long long*)(lds + (impA ^ rw)) = iv;
            if (l == 0)
                __hip_atomic_store(ackP, t + 1, __ATOMIC_RELAXED, __HIP_MEMORY_SCOPE_AGENT);
        }

        __syncthreads();   // END: dst rows + import + exports drained

        if (tid == 0 && doExpN)
            __hip_atomic_store(flagP, t + 1, __ATOMIC_RELAXED, __HIP_MEMORY_SCOPE_AGENT);
        rb ^= BUFB;
    }
}

extern "C" void kernel_launch(void* const* d_in, const int* in_sizes, int n_in,
                              void* d_out, int out_size, void* d_ws, size_t ws_size,
                              hipStream_t stream) {
    const float* x  = (const float*)d_in[0];
    const float* Wl = (const float*)d_in[1];
    const float* Wr = (const float*)d_in[2];
    const float* Wb = (const float*)d_in[3];
    const float* Gl = (const float*)d_in[4];
    const float* Gr = (const float*)d_in[5];
    const float* Gb = (const float*)d_in[6];
    float* out = (float*)d_out;
    char* ws = (char*)d_ws;

    _Float16* WT = (_Float16*)ws;                         // 278,528 B
    unsigned* brow = (unsigned*)(ws + 278528);            // 524,288 B (ring 4)
    int* flags = (int*)(ws + 802816);                     // 32,768 B
    unsigned* pmax = (unsigned*)(ws + 835584);            // 9,306,112 B

    prep_wt<<<272, 256, 0, stream>>>(Wl, Wr, Gl, Gr, WT);
    init_misc<<<B_, 256, 0, stream>>>(x, out, flags);

    void* args[] = { (void*)&x, (void*)&WT, (void*)&Wb, (void*)&Gb,
                     (void*)&pmax, (void*)&brow, (void*)&flags };
    hipLaunchCooperativeKernel((const void*)grcnn_main, dim3(B_ * 8), dim3(NTHR),
                               args, 0, stream);

    decode_out<<<1024, 256, 0, stream>>>(pmax, out);
}